// Round 8
// baseline (477.073 us; speedup 1.0000x reference)
//
#include <hip/hip_runtime.h>
#include <hip/hip_bf16.h>

#define NPTS 500000
#define NGR  64
#define TR   256
#define NT2  ((NPTS + TR - 1) / TR)   // 1954
#define GRID2 512

typedef __bf16 bf16x8 __attribute__((ext_vector_type(8)));
typedef float f32x4 __attribute__((ext_vector_type(4)));
typedef unsigned int u32x4 __attribute__((ext_vector_type(4)));

// ---- workspace layout (bytes), all 16B aligned ----
#define OFF_OUTACC 6144     // u32[8192]: order-preserving max accum
#define OFF_CBIAS  38912    // f32[8192]: per-graph GEMM1 bias row
#define OFF_W1PT   71680    // f32[512] : W1[128:131]^T padded [128][4] (plain)
#define OFF_W1AT   73728    // u16[8192] : bf16 W1[64:128]^T [n=128][k=64], XOR-swizzled
#define OFF_W2T    90112    // u16[16384]: bf16 W2^T [n=128][k=128], XOR-swizzled
// W1AT|W2T contiguous: one 49152-B region staged to LDS in k_main.

// order-preserving float->u32 map (max over u32 == max over float)
__device__ __forceinline__ unsigned mapf(float f) {
    union { float f; unsigned u; } v; v.f = f;
    return ((int)v.u >= 0) ? (v.u | 0x80000000u) : ~v.u;
}

#define GLOAD_LDS16(g, l) __builtin_amdgcn_global_load_lds(                 \
    (__attribute__((address_space(1))) void*)(g),                           \
    (__attribute__((address_space(3))) void*)(l), 16, 0, 0)

// ---- fused pre-pass (one 1024-thread block per graph): r7-proven.
//      distributed prep (swizzled W transposes, outacc init) +
//      COM (fp64) + argmin (truncated key) + cbias. No atomics. ----
__global__ __launch_bounds__(1024) void k_pre(
                      const float* __restrict__ pos,
                      const int* __restrict__ batch,
                      const float* __restrict__ x,
                      const float* __restrict__ W1,
                      const float* __restrict__ b1,
                      const float* __restrict__ W2,
                      const float* __restrict__ lfr,
                      unsigned short* __restrict__ W1aT,
                      unsigned short* __restrict__ W2T,
                      float* __restrict__ W1pT,
                      unsigned* __restrict__ outacc,
                      float* __restrict__ cbias,
                      float* __restrict__ outf) {
    __shared__ double sd[16][3];
    __shared__ unsigned long long sk[16];
    __shared__ double scom[3];
    __shared__ int sid;
    __shared__ float sposd[3];
    __shared__ float sp[4][128];
    __shared__ int sse[2];

    int g = blockIdx.x, t = threadIdx.x;
    int lane = t & 63, wv = t >> 6;   // wv 0..15

    // ---- distributed prep: 64*1024 = 65536 threads cover all items ----
    {
        int i = g * 1024 + t;
        if (i < 8192) {
            outacc[i] = 0u;
            int n = i >> 6, k = i & 63;
            unsigned short v = (unsigned short)(__builtin_bit_cast(unsigned, (float)(__bf16)W1[(64 + k) * 128 + n]) >> 16);
            W1aT[i ^ ((n & 7) << 3)] = v;
        } else if (i < 8192 + 16384) {
            int j = i - 8192; int n = j >> 7, k = j & 127;
            unsigned short v = (unsigned short)(__builtin_bit_cast(unsigned, (float)(__bf16)W2[k * 128 + n]) >> 16);
            W2T[j ^ ((n & 7) << 3)] = v;
        } else if (i < 8192 + 16384 + 512) {
            int j = i - 24576; int n = j >> 2, q = j & 3;
            W1pT[j] = (q < 3) ? W1[(128 + q) * 128 + n] : 0.f;
        }
    }

    // ---- own-range binary search (batch is sorted) ----
    if (t < 2) {
        int target = g + t;
        int lo = 0, hi = NPTS;
        while (lo < hi) {
            int mid = (lo + hi) >> 1;
            if (batch[mid] < target) lo = mid + 1; else hi = mid;
        }
        sse[t] = lo;
    }
    __syncthreads();
    int s = sse[0], e = sse[1];

    // pass 1: fp64 position sums
    double sx = 0.0, sy = 0.0, sz = 0.0;
    for (int i = s + t; i < e; i += 1024) {
        sx += (double)pos[i * 3 + 0];
        sy += (double)pos[i * 3 + 1];
        sz += (double)pos[i * 3 + 2];
    }
    #pragma unroll
    for (int m = 1; m < 64; m <<= 1) {
        sx += __shfl_xor(sx, m);
        sy += __shfl_xor(sy, m);
        sz += __shfl_xor(sz, m);
    }
    if (lane == 0) { sd[wv][0] = sx; sd[wv][1] = sy; sd[wv][2] = sz; }
    __syncthreads();
    if (t == 0) {
        double ax = 0.0, ay = 0.0, az = 0.0;
        for (int q = 0; q < 16; ++q) { ax += sd[q][0]; ay += sd[q][1]; az += sd[q][2]; }
        double cnt = (double)(e - s);
        double rc = 1.0 / (cnt > 1.0 ? cnt : 1.0);
        scom[0] = ax * rc; scom[1] = ay * rc; scom[2] = az * rc;
    }
    __syncthreads();
    double cx = scom[0], cy = scom[1], cz = scom[2];

    // pass 2: argmin of fp64 d2, key = (trunc d2-bits) | id
    unsigned long long key = ~0ULL;
    for (int i = s + t; i < e; i += 1024) {
        double dx = (double)pos[i * 3 + 0] - cx;
        double dy = (double)pos[i * 3 + 1] - cy;
        double dz = (double)pos[i * 3 + 2] - cz;
        double d2 = __builtin_fma(dx, dx, __builtin_fma(dy, dy, dz * dz));
        unsigned long long b = __builtin_bit_cast(unsigned long long, d2);
        unsigned long long k2 = (b & ~0xFFFFFULL) | (unsigned long long)i;
        key = k2 < key ? k2 : key;
    }
    #pragma unroll
    for (int m = 1; m < 64; m <<= 1) {
        unsigned long long o = __shfl_xor(key, m);
        key = o < key ? o : key;
    }
    if (lane == 0) sk[wv] = key;
    __syncthreads();
    if (t == 0) {
        unsigned long long k = sk[0];
        for (int q = 1; q < 16; ++q) if (sk[q] < k) k = sk[q];
        int id = (int)(k & 0xFFFFFULL);
        if (id > NPTS - 1) id = NPTS - 1;
        sid = id;
    }
    __syncthreads();
    int id = sid;

    if (t < 3) {
        float p = pos[id * 3 + t];
        sposd[t] = p;
        outf[8192 + g * 3 + t] = p;
    }
    if (t == 4) outf[8192 + 192 + g] = (float)batch[id];
    if (t < 9) outf[8192 + 256 + g * 9 + t] = lfr[id * 9 + t];

    // cbias: 4-way split over k, then ordered combine
    if (t < 512) {
        int c = t & 127, p = t >> 7;
        float part = 0.f;
        #pragma unroll
        for (int kq = 0; kq < 16; ++kq) {
            int k = p * 16 + kq;
            float xd = x[id * 64 + k];
            part += xd * (W1[k * 128 + c] - W1[(64 + k) * 128 + c]);
        }
        sp[p][c] = part;
    }
    __syncthreads();
    if (t < 128) {
        int c = t;
        float sv = b1[c] + sp[0][c] + sp[1][c] + sp[2][c] + sp[3][c];
        sv -= sposd[0] * W1[128 * 128 + c] + sposd[1] * W1[129 * 128 + c] + sposd[2] * W1[130 * 128 + c];
        cbias[g * 128 + c] = sv;
    }
}

// ---- main: r1 structure with LDS cut to EXACTLY 81920 B -> 2 blocks/CU.
//      (512,2) empirically = 2-blocks/CU register target (128-VGPR cap; r1 fit
//      at 108). h stripe shrunk [32][136]->[16][128] XOR-swizzled by
//      serializing GEMM2 into u=0/u=1 passes over the same stripe.
//      No fused tail (threadfence suspect in r7's 90->154; sflag would
//      break the 81920 budget). W stays LDS-sourced (global B spills, r6). ----
__global__ __launch_bounds__(512, 2) void k_main(
    const float* __restrict__ x,
    const float* __restrict__ pos,
    const int* __restrict__ batch,
    const unsigned short* __restrict__ W1aT,
    const unsigned short* __restrict__ W2T,
    const float* __restrict__ W1pT,
    const float* __restrict__ cbias,
    unsigned* __restrict__ outacc)
{
    // [0,16384): W1aT swizzled bf16 [128][64]
    // [16384,49152): W2T swizzled bf16 [128][128]
    // [49152,81920): h stripes: 8 waves x [16][128] bf16 XOR-swizzled (4096 B)
    __shared__ alignas(16) unsigned char smem[81920];

    const int tid  = threadIdx.x;        // 0..511
    const int w    = tid >> 6;           // 0..7
    const int lane = tid & 63;
    const int quad = lane >> 4;
    const int mr   = lane & 15;

    // stage W once (linear copy; global layout is pre-swizzled; 3072 x 16B)
    #pragma unroll
    for (int i = 0; i < 6; ++i)
        GLOAD_LDS16((const char*)W1aT + (i * 512 + tid) * 16,
                    (char*)smem + (i * 512 + tid) * 16);

    // tile-invariant: B-ext fragments for pos.W1p K-extension
    bf16x8 bfrE[8];
    #pragma unroll
    for (int t8 = 0; t8 < 8; ++t8) {
        f32x4 wp = *(const f32x4*)(W1pT + (t8 * 16 + mr) * 4);
        bf16x8 e = (bf16x8){0, 0, 0, 0, 0, 0, 0, 0};
        if (quad == 0) { e[0] = (__bf16)wp[0]; e[1] = (__bf16)wp[1]; e[2] = (__bf16)wp[2]; }
        bfrE[t8] = e;
    }

    __syncthreads();   // W staged; the only block-wide barrier in this kernel

    const unsigned short* sW1 = (const unsigned short*)smem;
    const unsigned short* sW2 = (const unsigned short*)(smem + 16384);
    __bf16* hsb = (__bf16*)(smem + 49152) + w * 2048;   // [16][128] swizzled
    const unsigned short* hss = (const unsigned short*)hsb;

    for (int t = blockIdx.x; t < NT2; t += GRID2) {
        const int row0 = t * TR + 32 * w;   // this wave's 32 global rows

        // ---- A loads, direct global (issued first, 8x dwordx4) ----
        f32x4 av[2][4];
        #pragma unroll
        for (int u = 0; u < 2; ++u) {
            int gr2 = row0 + 16 * u + mr; if (gr2 > NPTS - 1) gr2 = NPTS - 1;
            const float* xp = x + (size_t)gr2 * 64 + quad * 8;
            av[u][0] = *(const f32x4*)(xp);
            av[u][1] = *(const f32x4*)(xp + 4);
            av[u][2] = *(const f32x4*)(xp + 32);
            av[u][3] = *(const f32x4*)(xp + 36);
        }

        // ---- per-tile meta (overlaps A-load latency) ----
        int rowg[2][4]; bool rowv[2][4];
        #pragma unroll
        for (int u = 0; u < 2; ++u)
            #pragma unroll
            for (int r = 0; r < 4; ++r) {
                int gr = row0 + 16 * u + quad * 4 + r;
                rowv[u][r] = (gr < NPTS);
                rowg[u][r] = batch[gr < NPTS ? gr : NPTS - 1];
            }
        int gf = batch[row0 < NPTS ? row0 : NPTS - 1];
        int rl = row0 + 31; if (rl > NPTS - 1) rl = NPTS - 1;
        int gl = batch[rl];
        float cb0[8];
        #pragma unroll
        for (int t8 = 0; t8 < 8; ++t8) cb0[t8] = cbias[gf * 128 + t8 * 16 + mr];
        float pE[2][3];
        #pragma unroll
        for (int u = 0; u < 2; ++u) {
            int gp = row0 + 16 * u + mr; if (gp > NPTS - 1) gp = NPTS - 1;
            pE[u][0] = pos[gp * 3 + 0];
            pE[u][1] = pos[gp * 3 + 1];
            pE[u][2] = pos[gp * 3 + 2];
        }

        // ---- A fragments ----
        bf16x8 afr[2][2];
        #pragma unroll
        for (int u = 0; u < 2; ++u)
            #pragma unroll
            for (int h = 0; h < 2; ++h) {
                f32x4 va = av[u][2 * h], vb = av[u][2 * h + 1];
                bf16x8 a;
                a[0] = (__bf16)va[0]; a[1] = (__bf16)va[1]; a[2] = (__bf16)va[2]; a[3] = (__bf16)va[3];
                a[4] = (__bf16)vb[0]; a[5] = (__bf16)vb[1]; a[6] = (__bf16)vb[2]; a[7] = (__bf16)vb[3];
                afr[u][h] = a;
            }

        // ---- GEMM1 (B from swizzled LDS) + pos.W1p K-extension ----
        f32x4 acc[2][8];
        #pragma unroll
        for (int u = 0; u < 2; ++u)
            #pragma unroll
            for (int t8 = 0; t8 < 8; ++t8) acc[u][t8] = (f32x4){0.f, 0.f, 0.f, 0.f};
        #pragma unroll
        for (int t8 = 0; t8 < 8; ++t8) {
            int n = t8 * 16 + mr;
            int sw = (n & 7) << 3;
            bf16x8 bv0 = __builtin_bit_cast(bf16x8, *(const u32x4*)(sW1 + ((n * 64 + quad * 8) ^ sw)));
            bf16x8 bv1 = __builtin_bit_cast(bf16x8, *(const u32x4*)(sW1 + ((n * 64 + 32 + quad * 8) ^ sw)));
            #pragma unroll
            for (int u = 0; u < 2; ++u) {
                acc[u][t8] = __builtin_amdgcn_mfma_f32_16x16x32_bf16(afr[u][0], bv0, acc[u][t8], 0, 0, 0);
                acc[u][t8] = __builtin_amdgcn_mfma_f32_16x16x32_bf16(afr[u][1], bv1, acc[u][t8], 0, 0, 0);
            }
        }
        bf16x8 aE[2];
        #pragma unroll
        for (int u = 0; u < 2; ++u) {
            bf16x8 a = (bf16x8){0, 0, 0, 0, 0, 0, 0, 0};
            if (quad == 0) { a[0] = (__bf16)pE[u][0]; a[1] = (__bf16)pE[u][1]; a[2] = (__bf16)pE[u][2]; }
            aE[u] = a;
        }
        #pragma unroll
        for (int t8 = 0; t8 < 8; ++t8)
            #pragma unroll
            for (int u = 0; u < 2; ++u)
                acc[u][t8] = __builtin_amdgcn_mfma_f32_16x16x32_bf16(aE[u], bfrE[t8], acc[u][t8], 0, 0, 0);

        // ---- epilogue1 + GEMM2, serialized per u through the [16][128] stripe ----
        f32x4 acc2[2][8];
        #pragma unroll
        for (int u = 0; u < 2; ++u)
            #pragma unroll
            for (int t8 = 0; t8 < 8; ++t8) acc2[u][t8] = (f32x4){0.f, 0.f, 0.f, 0.f};
        #pragma unroll
        for (int u = 0; u < 2; ++u) {
            // h(u) = relu(acc[u] + cbias[g]) -> wave-private swizzled stripe
            #pragma unroll
            for (int r = 0; r < 4; ++r) {
                int lrow = quad * 4 + r;
                int g = rowg[u][r];
                bool odd = (g != gf);
                int sw = (lrow & 7) << 3;
                #pragma unroll
                for (int t8 = 0; t8 < 8; ++t8) {
                    float cbv = cb0[t8];
                    if (odd) cbv = cbias[g * 128 + t8 * 16 + mr];
                    float v = fmaxf(acc[u][t8][r] + cbv, 0.f);
                    hsb[lrow * 128 + ((t8 * 16 + mr) ^ sw)] = (__bf16)v;
                }
            }
            // no barrier: same-wave RAW through own stripe (DS ops are
            // program-ordered per wave; compiler tracks the aliasing)
            int swr = (mr & 7) << 3;
            #pragma unroll
            for (int kk = 0; kk < 4; ++kk) {
                bf16x8 a2 = __builtin_bit_cast(bf16x8,
                    *(const u32x4*)(hss + mr * 128 + ((kk * 32 + quad * 8) ^ swr)));
                #pragma unroll
                for (int t8 = 0; t8 < 8; ++t8) {
                    int n = t8 * 16 + mr;
                    bf16x8 bv = __builtin_bit_cast(bf16x8,
                        *(const u32x4*)(sW2 + ((n * 128 + kk * 32 + quad * 8) ^ ((n & 7) << 3))));
                    acc2[u][t8] = __builtin_amdgcn_mfma_f32_16x16x32_bf16(a2, bv, acc2[u][t8], 0, 0, 0);
                }
            }
        }

        // ---- epilogue2: per-graph column max -> global atomicMax (r1-proven) ----
        for (int g = gf; g <= gl; ++g) {
            #pragma unroll
            for (int t8 = 0; t8 < 8; ++t8) {
                float m = -INFINITY;
                #pragma unroll
                for (int u = 0; u < 2; ++u)
                    #pragma unroll
                    for (int r = 0; r < 4; ++r)
                        if (rowv[u][r] && rowg[u][r] == g) m = fmaxf(m, acc2[u][t8][r]);
                m = fmaxf(m, __shfl_xor(m, 16));
                m = fmaxf(m, __shfl_xor(m, 32));
                unsigned mb = __builtin_bit_cast(unsigned, m);
                if (quad == 0 && mb != 0xFF800000u)
                    atomicMax(&outacc[g * 128 + t8 * 16 + mr], mapf(m));
            }
        }
    }
}

__global__ void k_out(const unsigned* __restrict__ outacc,
                      const float* __restrict__ b2v,
                      float* __restrict__ outf) {
    int i = blockIdx.x * 256 + threadIdx.x;   // 8192 threads
    unsigned key = outacc[i];
    float v;
    if (key == 0u) {
        v = -300.f;   // diagnostic: never updated
    } else {
        unsigned bits = (key & 0x80000000u) ? (key & 0x7FFFFFFFu) : ~key;
        union { unsigned u; float f; } c; c.u = bits; v = c.f;
    }
    outf[i] = v + b2v[i & 127];
}

extern "C" void kernel_launch(void* const* d_in, const int* in_sizes, int n_in,
                              void* d_out, int out_size, void* d_ws, size_t ws_size,
                              hipStream_t stream) {
    const float* x   = (const float*)d_in[0];
    const float* pos = (const float*)d_in[1];
    const int*   bat = (const int*)d_in[2];
    const float* lfr = (const float*)d_in[3];
    const float* W1  = (const float*)d_in[4];
    const float* b1  = (const float*)d_in[5];
    const float* W2  = (const float*)d_in[6];
    const float* b2v = (const float*)d_in[7];
    float* outf = (float*)d_out;

    char* ws = (char*)d_ws;
    unsigned*       outacc = (unsigned*)(ws + OFF_OUTACC);
    float*          cbias  = (float*)(ws + OFF_CBIAS);
    float*          W1pT   = (float*)(ws + OFF_W1PT);
    unsigned short* W1aT   = (unsigned short*)(ws + OFF_W1AT);
    unsigned short* W2T    = (unsigned short*)(ws + OFF_W2T);

    k_pre<<<64, 1024, 0, stream>>>(pos, bat, x, W1, b1, W2, lfr,
                                   W1aT, W2T, W1pT, outacc, cbias, outf);
    k_main<<<GRID2, 512, 0, stream>>>(x, pos, bat, W1aT, W2T, W1pT, cbias, outacc);
    k_out<<<32, 256, 0, stream>>>(outacc, b2v, outf);
}

// Round 9
// 300.810 us; speedup vs baseline: 1.5860x; 1.5860x over previous
//
#include <hip/hip_runtime.h>
#include <hip/hip_bf16.h>

#define NPTS 500000
#define NGR  64
#define TR   128
#define NT2  ((NPTS + TR - 1) / TR)   // 3907
#define GRID2 1024

typedef __bf16 bf16x8 __attribute__((ext_vector_type(8)));
typedef float f32x4 __attribute__((ext_vector_type(4)));
typedef unsigned int u32x4 __attribute__((ext_vector_type(4)));

// ---- workspace layout (bytes), all 16B aligned ----
#define OFF_OUTACC 6144     // u32[8192]: order-preserving max accum
#define OFF_CBIAS  38912    // f32[8192]: per-graph GEMM1 bias row
#define OFF_W1PT   71680    // f32[512] : W1[128:131]^T padded [128][4] (plain)
#define OFF_W1AT   73728    // u16[8192] : bf16 W1[64:128]^T [n=128][k=64], XOR-swizzled
#define OFF_W2T    90112    // u16[16384]: bf16 W2^T [n=128][k=128], XOR-swizzled
// W1AT|W2T contiguous: one 49152-B region staged to LDS in k_main.

// order-preserving float->u32 map (max over u32 == max over float)
__device__ __forceinline__ unsigned mapf(float f) {
    union { float f; unsigned u; } v; v.f = f;
    return ((int)v.u >= 0) ? (v.u | 0x80000000u) : ~v.u;
}

#define GLOAD_LDS16(g, l) __builtin_amdgcn_global_load_lds(                 \
    (__attribute__((address_space(1))) void*)(g),                           \
    (__attribute__((address_space(3))) void*)(l), 16, 0, 0)

// ---- fused pre-pass (one 1024-thread block per graph): proven r7/r8.
//      distributed prep (swizzled W transposes, outacc init) +
//      COM (fp64) + argmin (truncated key) + cbias. No atomics. ----
__global__ __launch_bounds__(1024) void k_pre(
                      const float* __restrict__ pos,
                      const int* __restrict__ batch,
                      const float* __restrict__ x,
                      const float* __restrict__ W1,
                      const float* __restrict__ b1,
                      const float* __restrict__ W2,
                      const float* __restrict__ lfr,
                      unsigned short* __restrict__ W1aT,
                      unsigned short* __restrict__ W2T,
                      float* __restrict__ W1pT,
                      unsigned* __restrict__ outacc,
                      float* __restrict__ cbias,
                      float* __restrict__ outf) {
    __shared__ double sd[16][3];
    __shared__ unsigned long long sk[16];
    __shared__ double scom[3];
    __shared__ int sid;
    __shared__ float sposd[3];
    __shared__ float sp[4][128];
    __shared__ int sse[2];

    int g = blockIdx.x, t = threadIdx.x;
    int lane = t & 63, wv = t >> 6;   // wv 0..15

    // ---- distributed prep: 64*1024 = 65536 threads cover all items ----
    {
        int i = g * 1024 + t;
        if (i < 8192) {
            outacc[i] = 0u;
            int n = i >> 6, k = i & 63;
            unsigned short v = (unsigned short)(__builtin_bit_cast(unsigned, (float)(__bf16)W1[(64 + k) * 128 + n]) >> 16);
            W1aT[i ^ ((n & 7) << 3)] = v;
        } else if (i < 8192 + 16384) {
            int j = i - 8192; int n = j >> 7, k = j & 127;
            unsigned short v = (unsigned short)(__builtin_bit_cast(unsigned, (float)(__bf16)W2[k * 128 + n]) >> 16);
            W2T[j ^ ((n & 7) << 3)] = v;
        } else if (i < 8192 + 16384 + 512) {
            int j = i - 24576; int n = j >> 2, q = j & 3;
            W1pT[j] = (q < 3) ? W1[(128 + q) * 128 + n] : 0.f;
        }
    }

    // ---- own-range binary search (batch is sorted) ----
    if (t < 2) {
        int target = g + t;
        int lo = 0, hi = NPTS;
        while (lo < hi) {
            int mid = (lo + hi) >> 1;
            if (batch[mid] < target) lo = mid + 1; else hi = mid;
        }
        sse[t] = lo;
    }
    __syncthreads();
    int s = sse[0], e = sse[1];

    // pass 1: fp64 position sums
    double sx = 0.0, sy = 0.0, sz = 0.0;
    for (int i = s + t; i < e; i += 1024) {
        sx += (double)pos[i * 3 + 0];
        sy += (double)pos[i * 3 + 1];
        sz += (double)pos[i * 3 + 2];
    }
    #pragma unroll
    for (int m = 1; m < 64; m <<= 1) {
        sx += __shfl_xor(sx, m);
        sy += __shfl_xor(sy, m);
        sz += __shfl_xor(sz, m);
    }
    if (lane == 0) { sd[wv][0] = sx; sd[wv][1] = sy; sd[wv][2] = sz; }
    __syncthreads();
    if (t == 0) {
        double ax = 0.0, ay = 0.0, az = 0.0;
        for (int q = 0; q < 16; ++q) { ax += sd[q][0]; ay += sd[q][1]; az += sd[q][2]; }
        double cnt = (double)(e - s);
        double rc = 1.0 / (cnt > 1.0 ? cnt : 1.0);
        scom[0] = ax * rc; scom[1] = ay * rc; scom[2] = az * rc;
    }
    __syncthreads();
    double cx = scom[0], cy = scom[1], cz = scom[2];

    // pass 2: argmin of fp64 d2, key = (trunc d2-bits) | id
    unsigned long long key = ~0ULL;
    for (int i = s + t; i < e; i += 1024) {
        double dx = (double)pos[i * 3 + 0] - cx;
        double dy = (double)pos[i * 3 + 1] - cy;
        double dz = (double)pos[i * 3 + 2] - cz;
        double d2 = __builtin_fma(dx, dx, __builtin_fma(dy, dy, dz * dz));
        unsigned long long b = __builtin_bit_cast(unsigned long long, d2);
        unsigned long long k2 = (b & ~0xFFFFFULL) | (unsigned long long)i;
        key = k2 < key ? k2 : key;
    }
    #pragma unroll
    for (int m = 1; m < 64; m <<= 1) {
        unsigned long long o = __shfl_xor(key, m);
        key = o < key ? o : key;
    }
    if (lane == 0) sk[wv] = key;
    __syncthreads();
    if (t == 0) {
        unsigned long long k = sk[0];
        for (int q = 1; q < 16; ++q) if (sk[q] < k) k = sk[q];
        int id = (int)(k & 0xFFFFFULL);
        if (id > NPTS - 1) id = NPTS - 1;
        sid = id;
    }
    __syncthreads();
    int id = sid;

    if (t < 3) {
        float p = pos[id * 3 + t];
        sposd[t] = p;
        outf[8192 + g * 3 + t] = p;
    }
    if (t == 4) outf[8192 + 192 + g] = (float)batch[id];
    if (t < 9) outf[8192 + 256 + g * 9 + t] = lfr[id * 9 + t];

    // cbias: 4-way split over k, then ordered combine
    if (t < 512) {
        int c = t & 127, p = t >> 7;
        float part = 0.f;
        #pragma unroll
        for (int kq = 0; kq < 16; ++kq) {
            int k = p * 16 + kq;
            float xd = x[id * 64 + k];
            part += xd * (W1[k * 128 + c] - W1[(64 + k) * 128 + c]);
        }
        sp[p][c] = part;
    }
    __syncthreads();
    if (t < 128) {
        int c = t;
        float sv = b1[c] + sp[0][c] + sp[1][c] + sp[2][c] + sp[3][c];
        sv -= sposd[0] * W1[128 * 128 + c] + sposd[1] * W1[129 * 128 + c] + sposd[2] * W1[130 * 128 + c];
        cbias[g * 128 + c] = sv;
    }
}

// ---- main: M=16 rows/wave (TR=128), 8 waves, (512,2). r1's exact two-phase
//      liveness (acc dies into h BEFORE acc2 exists), just half the
//      accumulators: acc[8]=32 VGPR, acc2[8]=32 VGPR -> peak demand ~95,
//      real headroom under the 128-VGPR (512,2) cap. LDS = 49152 (W, swizzled)
//      + 8 x [16][128] swizzled h stripes (4096 B) = 81920 EXACTLY ->
//      2 blocks/CU = 16 waves/CU. Zero barriers in the loop.
//      r8's u-serialization spilled because acc[1] stayed live across GEMM2
//      u=0 (acc2 64 + acc 32 > cap) -- do NOT reintroduce it. ----
__global__ __launch_bounds__(512, 2) void k_main(
    const float* __restrict__ x,
    const float* __restrict__ pos,
    const int* __restrict__ batch,
    const unsigned short* __restrict__ W1aT,
    const unsigned short* __restrict__ W2T,
    const float* __restrict__ W1pT,
    const float* __restrict__ cbias,
    unsigned* __restrict__ outacc)
{
    // [0,16384): W1aT swizzled bf16 [128][64]
    // [16384,49152): W2T swizzled bf16 [128][128]
    // [49152,81920): h stripes: 8 waves x [16][128] bf16 XOR-swizzled (4096 B)
    __shared__ alignas(16) unsigned char smem[81920];

    const int tid  = threadIdx.x;        // 0..511
    const int w    = tid >> 6;           // 0..7
    const int lane = tid & 63;
    const int quad = lane >> 4;
    const int mr   = lane & 15;

    // stage W once (linear copy; global layout is pre-swizzled; 3072 x 16B)
    #pragma unroll
    for (int i = 0; i < 6; ++i)
        GLOAD_LDS16((const char*)W1aT + (i * 512 + tid) * 16,
                    (char*)smem + (i * 512 + tid) * 16);

    // tile-invariant: B-ext fragments for pos.W1p K-extension
    bf16x8 bfrE[8];
    #pragma unroll
    for (int t8 = 0; t8 < 8; ++t8) {
        f32x4 wp = *(const f32x4*)(W1pT + (t8 * 16 + mr) * 4);
        bf16x8 e = (bf16x8){0, 0, 0, 0, 0, 0, 0, 0};
        if (quad == 0) { e[0] = (__bf16)wp[0]; e[1] = (__bf16)wp[1]; e[2] = (__bf16)wp[2]; }
        bfrE[t8] = e;
    }

    __syncthreads();   // W staged; the only block-wide barrier in this kernel

    const unsigned short* sW1 = (const unsigned short*)smem;
    const unsigned short* sW2 = (const unsigned short*)(smem + 16384);
    __bf16* hsb = (__bf16*)(smem + 49152) + w * 2048;   // [16][128] swizzled
    const unsigned short* hss = (const unsigned short*)hsb;

    for (int t = blockIdx.x; t < NT2; t += GRID2) {
        const int row0 = t * TR + 16 * w;   // this wave's 16 global rows

        // ---- A loads, direct global (issued first, 4x dwordx4) ----
        f32x4 av0, av1, av2, av3;
        {
            int gr2 = row0 + mr; if (gr2 > NPTS - 1) gr2 = NPTS - 1;
            const float* xp = x + (size_t)gr2 * 64 + quad * 8;
            av0 = *(const f32x4*)(xp);
            av1 = *(const f32x4*)(xp + 4);
            av2 = *(const f32x4*)(xp + 32);
            av3 = *(const f32x4*)(xp + 36);
        }

        // ---- per-tile meta (overlaps A-load latency) ----
        int rowg[4]; bool rowv[4];
        #pragma unroll
        for (int r = 0; r < 4; ++r) {
            int gr = row0 + quad * 4 + r;
            rowv[r] = (gr < NPTS);
            rowg[r] = batch[gr < NPTS ? gr : NPTS - 1];
        }
        int gf = batch[row0 < NPTS ? row0 : NPTS - 1];
        int rl = row0 + 15; if (rl > NPTS - 1) rl = NPTS - 1;
        int gl = batch[rl];
        float cb0[8];
        #pragma unroll
        for (int t8 = 0; t8 < 8; ++t8) cb0[t8] = cbias[gf * 128 + t8 * 16 + mr];
        // A-ext fragment: pos of this lane's row in k-slots 0..2 (quad 0 only)
        bf16x8 aE = (bf16x8){0, 0, 0, 0, 0, 0, 0, 0};
        {
            int gp = row0 + mr; if (gp > NPTS - 1) gp = NPTS - 1;
            if (quad == 0) {
                aE[0] = (__bf16)pos[gp * 3 + 0];
                aE[1] = (__bf16)pos[gp * 3 + 1];
                aE[2] = (__bf16)pos[gp * 3 + 2];
            }
        }

        // ---- A fragments ----
        bf16x8 afr0, afr1;
        afr0[0] = (__bf16)av0[0]; afr0[1] = (__bf16)av0[1]; afr0[2] = (__bf16)av0[2]; afr0[3] = (__bf16)av0[3];
        afr0[4] = (__bf16)av1[0]; afr0[5] = (__bf16)av1[1]; afr0[6] = (__bf16)av1[2]; afr0[7] = (__bf16)av1[3];
        afr1[0] = (__bf16)av2[0]; afr1[1] = (__bf16)av2[1]; afr1[2] = (__bf16)av2[2]; afr1[3] = (__bf16)av2[3];
        afr1[4] = (__bf16)av3[0]; afr1[5] = (__bf16)av3[1]; afr1[6] = (__bf16)av3[2]; afr1[7] = (__bf16)av3[3];

        // ---- GEMM1 (B from swizzled LDS) + pos.W1p K-extension ----
        f32x4 acc[8];
        #pragma unroll
        for (int t8 = 0; t8 < 8; ++t8) acc[t8] = (f32x4){0.f, 0.f, 0.f, 0.f};
        #pragma unroll
        for (int t8 = 0; t8 < 8; ++t8) {
            int n = t8 * 16 + mr;
            int sw = (n & 7) << 3;
            bf16x8 bv0 = __builtin_bit_cast(bf16x8, *(const u32x4*)(sW1 + ((n * 64 + quad * 8) ^ sw)));
            bf16x8 bv1 = __builtin_bit_cast(bf16x8, *(const u32x4*)(sW1 + ((n * 64 + 32 + quad * 8) ^ sw)));
            acc[t8] = __builtin_amdgcn_mfma_f32_16x16x32_bf16(afr0, bv0, acc[t8], 0, 0, 0);
            acc[t8] = __builtin_amdgcn_mfma_f32_16x16x32_bf16(afr1, bv1, acc[t8], 0, 0, 0);
            acc[t8] = __builtin_amdgcn_mfma_f32_16x16x32_bf16(aE, bfrE[t8], acc[t8], 0, 0, 0);
        }

        // ---- epilogue1: h = relu(acc + cbias[g]) -> wave-private swizzled stripe
        //      (acc fully dies here, BEFORE acc2 exists: r1's proven liveness) ----
        #pragma unroll
        for (int r = 0; r < 4; ++r) {
            int lrow = quad * 4 + r;
            int g = rowg[r];
            bool odd = (g != gf);
            int sw = (lrow & 7) << 3;
            #pragma unroll
            for (int t8 = 0; t8 < 8; ++t8) {
                float cbv = cb0[t8];
                if (odd) cbv = cbias[g * 128 + t8 * 16 + mr];
                float v = fmaxf(acc[t8][r] + cbv, 0.f);
                hsb[lrow * 128 + ((t8 * 16 + mr) ^ sw)] = (__bf16)v;
            }
        }
        // no barrier: GEMM2 reads only this wave's own stripe (same-wave RAW)

        // ---- GEMM2 (A from own h stripe, B from swizzled LDS) ----
        f32x4 acc2[8];
        #pragma unroll
        for (int t8 = 0; t8 < 8; ++t8) acc2[t8] = (f32x4){0.f, 0.f, 0.f, 0.f};
        int swr = (mr & 7) << 3;
        #pragma unroll
        for (int kk = 0; kk < 4; ++kk) {
            bf16x8 a2 = __builtin_bit_cast(bf16x8,
                *(const u32x4*)(hss + mr * 128 + ((kk * 32 + quad * 8) ^ swr)));
            #pragma unroll
            for (int t8 = 0; t8 < 8; ++t8) {
                int n = t8 * 16 + mr;
                bf16x8 bv = __builtin_bit_cast(bf16x8,
                    *(const u32x4*)(sW2 + ((n * 128 + kk * 32 + quad * 8) ^ ((n & 7) << 3))));
                acc2[t8] = __builtin_amdgcn_mfma_f32_16x16x32_bf16(a2, bv, acc2[t8], 0, 0, 0);
            }
        }

        // ---- epilogue2: per-graph column max -> global atomicMax (r1-proven) ----
        for (int g = gf; g <= gl; ++g) {
            #pragma unroll
            for (int t8 = 0; t8 < 8; ++t8) {
                float m = -INFINITY;
                #pragma unroll
                for (int r = 0; r < 4; ++r)
                    if (rowv[r] && rowg[r] == g) m = fmaxf(m, acc2[t8][r]);
                m = fmaxf(m, __shfl_xor(m, 16));
                m = fmaxf(m, __shfl_xor(m, 32));
                unsigned mb = __builtin_bit_cast(unsigned, m);
                if (quad == 0 && mb != 0xFF800000u)
                    atomicMax(&outacc[g * 128 + t8 * 16 + mr], mapf(m));
            }
        }
    }
}

__global__ void k_out(const unsigned* __restrict__ outacc,
                      const float* __restrict__ b2v,
                      float* __restrict__ outf) {
    int i = blockIdx.x * 256 + threadIdx.x;   // 8192 threads
    unsigned key = outacc[i];
    float v;
    if (key == 0u) {
        v = -300.f;   // diagnostic: never updated
    } else {
        unsigned bits = (key & 0x80000000u) ? (key & 0x7FFFFFFFu) : ~key;
        union { unsigned u; float f; } c; c.u = bits; v = c.f;
    }
    outf[i] = v + b2v[i & 127];
}

extern "C" void kernel_launch(void* const* d_in, const int* in_sizes, int n_in,
                              void* d_out, int out_size, void* d_ws, size_t ws_size,
                              hipStream_t stream) {
    const float* x   = (const float*)d_in[0];
    const float* pos = (const float*)d_in[1];
    const int*   bat = (const int*)d_in[2];
    const float* lfr = (const float*)d_in[3];
    const float* W1  = (const float*)d_in[4];
    const float* b1  = (const float*)d_in[5];
    const float* W2  = (const float*)d_in[6];
    const float* b2v = (const float*)d_in[7];
    float* outf = (float*)d_out;

    char* ws = (char*)d_ws;
    unsigned*       outacc = (unsigned*)(ws + OFF_OUTACC);
    float*          cbias  = (float*)(ws + OFF_CBIAS);
    float*          W1pT   = (float*)(ws + OFF_W1PT);
    unsigned short* W1aT   = (unsigned short*)(ws + OFF_W1AT);
    unsigned short* W2T    = (unsigned short*)(ws + OFF_W2T);

    k_pre<<<64, 1024, 0, stream>>>(pos, bat, x, W1, b1, W2, lfr,
                                   W1aT, W2T, W1pT, outacc, cbias, outf);
    k_main<<<GRID2, 512, 0, stream>>>(x, pos, bat, W1aT, W2T, W1pT, cbias, outacc);
    k_out<<<32, 256, 0, stream>>>(outacc, b2v, outf);
}

// Round 10
// 275.615 us; speedup vs baseline: 1.7309x; 1.0914x over previous
//
#include <hip/hip_runtime.h>
#include <hip/hip_bf16.h>

#define NPTS 500000
#define NGR  64
#define TR   128
#define NT2  ((NPTS + TR - 1) / TR)   // 3907
#define CHUNK 4
#define NBLK ((NT2 + CHUNK - 1) / CHUNK)   // 977

typedef __bf16 bf16x8 __attribute__((ext_vector_type(8)));
typedef float f32x4 __attribute__((ext_vector_type(4)));
typedef unsigned int u32x4 __attribute__((ext_vector_type(4)));

// ---- workspace layout (bytes), all 16B aligned ----
#define OFF_OUTACC 6144     // u32[8192]: order-preserving max accum
#define OFF_CBIAS  38912    // f32[8192]: per-graph GEMM1 bias row
#define OFF_W1PT   71680    // f32[512] : W1[128:131]^T padded [128][4] (plain)
#define OFF_W1AT   73728    // u16[8192] : bf16 W1[64:128]^T [n=128][k=64], XOR-swizzled
#define OFF_W2T    90112    // u16[16384]: bf16 W2^T [n=128][k=128], XOR-swizzled
// W1AT|W2T contiguous: one 49152-B region staged to LDS in k_main.

// order-preserving float->u32 map (max over u32 == max over float)
__device__ __forceinline__ unsigned mapf(float f) {
    union { float f; unsigned u; } v; v.f = f;
    return ((int)v.u >= 0) ? (v.u | 0x80000000u) : ~v.u;
}

#define GLOAD_LDS16(g, l) __builtin_amdgcn_global_load_lds(                 \
    (__attribute__((address_space(1))) void*)(g),                           \
    (__attribute__((address_space(3))) void*)(l), 16, 0, 0)

// ---- fused pre-pass (one 1024-thread block per graph): proven r7-r9.
//      distributed prep (swizzled W transposes, outacc init) +
//      COM (fp64) + argmin (truncated key) + cbias. No atomics. ----
__global__ __launch_bounds__(1024) void k_pre(
                      const float* __restrict__ pos,
                      const int* __restrict__ batch,
                      const float* __restrict__ x,
                      const float* __restrict__ W1,
                      const float* __restrict__ b1,
                      const float* __restrict__ W2,
                      const float* __restrict__ lfr,
                      unsigned short* __restrict__ W1aT,
                      unsigned short* __restrict__ W2T,
                      float* __restrict__ W1pT,
                      unsigned* __restrict__ outacc,
                      float* __restrict__ cbias,
                      float* __restrict__ outf) {
    __shared__ double sd[16][3];
    __shared__ unsigned long long sk[16];
    __shared__ double scom[3];
    __shared__ int sid;
    __shared__ float sposd[3];
    __shared__ float sp[4][128];
    __shared__ int sse[2];

    int g = blockIdx.x, t = threadIdx.x;
    int lane = t & 63, wv = t >> 6;   // wv 0..15

    // ---- distributed prep: 64*1024 = 65536 threads cover all items ----
    {
        int i = g * 1024 + t;
        if (i < 8192) {
            outacc[i] = 0u;
            int n = i >> 6, k = i & 63;
            unsigned short v = (unsigned short)(__builtin_bit_cast(unsigned, (float)(__bf16)W1[(64 + k) * 128 + n]) >> 16);
            W1aT[i ^ ((n & 7) << 3)] = v;
        } else if (i < 8192 + 16384) {
            int j = i - 8192; int n = j >> 7, k = j & 127;
            unsigned short v = (unsigned short)(__builtin_bit_cast(unsigned, (float)(__bf16)W2[k * 128 + n]) >> 16);
            W2T[j ^ ((n & 7) << 3)] = v;
        } else if (i < 8192 + 16384 + 512) {
            int j = i - 24576; int n = j >> 2, q = j & 3;
            W1pT[j] = (q < 3) ? W1[(128 + q) * 128 + n] : 0.f;
        }
    }

    // ---- own-range binary search (batch is sorted) ----
    if (t < 2) {
        int target = g + t;
        int lo = 0, hi = NPTS;
        while (lo < hi) {
            int mid = (lo + hi) >> 1;
            if (batch[mid] < target) lo = mid + 1; else hi = mid;
        }
        sse[t] = lo;
    }
    __syncthreads();
    int s = sse[0], e = sse[1];

    // pass 1: fp64 position sums
    double sx = 0.0, sy = 0.0, sz = 0.0;
    for (int i = s + t; i < e; i += 1024) {
        sx += (double)pos[i * 3 + 0];
        sy += (double)pos[i * 3 + 1];
        sz += (double)pos[i * 3 + 2];
    }
    #pragma unroll
    for (int m = 1; m < 64; m <<= 1) {
        sx += __shfl_xor(sx, m);
        sy += __shfl_xor(sy, m);
        sz += __shfl_xor(sz, m);
    }
    if (lane == 0) { sd[wv][0] = sx; sd[wv][1] = sy; sd[wv][2] = sz; }
    __syncthreads();
    if (t == 0) {
        double ax = 0.0, ay = 0.0, az = 0.0;
        for (int q = 0; q < 16; ++q) { ax += sd[q][0]; ay += sd[q][1]; az += sd[q][2]; }
        double cnt = (double)(e - s);
        double rc = 1.0 / (cnt > 1.0 ? cnt : 1.0);
        scom[0] = ax * rc; scom[1] = ay * rc; scom[2] = az * rc;
    }
    __syncthreads();
    double cx = scom[0], cy = scom[1], cz = scom[2];

    // pass 2: argmin of fp64 d2, key = (trunc d2-bits) | id
    unsigned long long key = ~0ULL;
    for (int i = s + t; i < e; i += 1024) {
        double dx = (double)pos[i * 3 + 0] - cx;
        double dy = (double)pos[i * 3 + 1] - cy;
        double dz = (double)pos[i * 3 + 2] - cz;
        double d2 = __builtin_fma(dx, dx, __builtin_fma(dy, dy, dz * dz));
        unsigned long long b = __builtin_bit_cast(unsigned long long, d2);
        unsigned long long k2 = (b & ~0xFFFFFULL) | (unsigned long long)i;
        key = k2 < key ? k2 : key;
    }
    #pragma unroll
    for (int m = 1; m < 64; m <<= 1) {
        unsigned long long o = __shfl_xor(key, m);
        key = o < key ? o : key;
    }
    if (lane == 0) sk[wv] = key;
    __syncthreads();
    if (t == 0) {
        unsigned long long k = sk[0];
        for (int q = 1; q < 16; ++q) if (sk[q] < k) k = sk[q];
        int id = (int)(k & 0xFFFFFULL);
        if (id > NPTS - 1) id = NPTS - 1;
        sid = id;
    }
    __syncthreads();
    int id = sid;

    if (t < 3) {
        float p = pos[id * 3 + t];
        sposd[t] = p;
        outf[8192 + g * 3 + t] = p;
    }
    if (t == 4) outf[8192 + 192 + g] = (float)batch[id];
    if (t < 9) outf[8192 + 256 + g * 9 + t] = lfr[id * 9 + t];

    // cbias: 4-way split over k, then ordered combine
    if (t < 512) {
        int c = t & 127, p = t >> 7;
        float part = 0.f;
        #pragma unroll
        for (int kq = 0; kq < 16; ++kq) {
            int k = p * 16 + kq;
            float xd = x[id * 64 + k];
            part += xd * (W1[k * 128 + c] - W1[(64 + k) * 128 + c]);
        }
        sp[p][c] = part;
    }
    __syncthreads();
    if (t < 128) {
        int c = t;
        float sv = b1[c] + sp[0][c] + sp[1][c] + sp[2][c] + sp[3][c];
        sv -= sposd[0] * W1[128 * 128 + c] + sposd[1] * W1[129 * 128 + c] + sposd[2] * W1[130 * 128 + c];
        cbias[g * 128 + c] = sv;
    }
}

// ---- main: r9 structure (M=16, 8 waves, (512,2), LDS 81920 -> 2 blocks/CU,
//      VGPR 96 clean) + ONE change: chunked contiguous tiles with next-tile
//      A-row prefetch (x: 4x dwordx4, pos: 3 scalars) into registers, issued
//      right after the current tile's fragments are extracted. The ~900-cycle
//      HBM latency then hides under GEMM1+epi1+GEMM2+epi2 instead of
//      serializing the loop (compiler can't hoist loads past the atomics).
//      Register budget: 96 + ~19 prefetch regs ~= 115 < 128 cap. ----
__global__ __launch_bounds__(512, 2) void k_main(
    const float* __restrict__ x,
    const float* __restrict__ pos,
    const int* __restrict__ batch,
    const unsigned short* __restrict__ W1aT,
    const unsigned short* __restrict__ W2T,
    const float* __restrict__ W1pT,
    const float* __restrict__ cbias,
    unsigned* __restrict__ outacc)
{
    // [0,16384): W1aT swizzled bf16 [128][64]
    // [16384,49152): W2T swizzled bf16 [128][128]
    // [49152,81920): h stripes: 8 waves x [16][128] bf16 XOR-swizzled (4096 B)
    __shared__ alignas(16) unsigned char smem[81920];

    const int tid  = threadIdx.x;        // 0..511
    const int w    = tid >> 6;           // 0..7
    const int lane = tid & 63;
    const int quad = lane >> 4;
    const int mr   = lane & 15;

    // stage W once (linear copy; global layout is pre-swizzled; 3072 x 16B)
    #pragma unroll
    for (int i = 0; i < 6; ++i)
        GLOAD_LDS16((const char*)W1aT + (i * 512 + tid) * 16,
                    (char*)smem + (i * 512 + tid) * 16);

    // tile-invariant: B-ext fragments for pos.W1p K-extension
    bf16x8 bfrE[8];
    #pragma unroll
    for (int t8 = 0; t8 < 8; ++t8) {
        f32x4 wp = *(const f32x4*)(W1pT + (t8 * 16 + mr) * 4);
        bf16x8 e = (bf16x8){0, 0, 0, 0, 0, 0, 0, 0};
        if (quad == 0) { e[0] = (__bf16)wp[0]; e[1] = (__bf16)wp[1]; e[2] = (__bf16)wp[2]; }
        bfrE[t8] = e;
    }

    __syncthreads();   // W staged; the only block-wide barrier in this kernel

    const unsigned short* sW1 = (const unsigned short*)smem;
    const unsigned short* sW2 = (const unsigned short*)(smem + 16384);
    __bf16* hsb = (__bf16*)(smem + 49152) + w * 2048;   // [16][128] swizzled
    const unsigned short* hss = (const unsigned short*)hsb;

    const int tb = blockIdx.x * CHUNK;
    int te = tb + CHUNK; if (te > NT2) te = NT2;

    // ---- prefetch first tile's A rows (x: 4x dwordx4, pos: 3 scalars) ----
    f32x4 av0, av1, av2, av3;
    float pv0, pv1, pv2;
    {
        int gr = tb * TR + 16 * w + mr; if (gr > NPTS - 1) gr = NPTS - 1;
        const float* xp = x + (size_t)gr * 64 + quad * 8;
        av0 = *(const f32x4*)(xp);
        av1 = *(const f32x4*)(xp + 4);
        av2 = *(const f32x4*)(xp + 32);
        av3 = *(const f32x4*)(xp + 36);
        pv0 = pos[gr * 3 + 0];
        pv1 = pos[gr * 3 + 1];
        pv2 = pos[gr * 3 + 2];
    }

    for (int t = tb; t < te; ++t) {
        const int row0 = t * TR + 16 * w;   // this wave's 16 global rows

        // ---- extract fragments from prefetched registers ----
        bf16x8 afr0, afr1;
        afr0[0] = (__bf16)av0[0]; afr0[1] = (__bf16)av0[1]; afr0[2] = (__bf16)av0[2]; afr0[3] = (__bf16)av0[3];
        afr0[4] = (__bf16)av1[0]; afr0[5] = (__bf16)av1[1]; afr0[6] = (__bf16)av1[2]; afr0[7] = (__bf16)av1[3];
        afr1[0] = (__bf16)av2[0]; afr1[1] = (__bf16)av2[1]; afr1[2] = (__bf16)av2[2]; afr1[3] = (__bf16)av2[3];
        afr1[4] = (__bf16)av3[0]; afr1[5] = (__bf16)av3[1]; afr1[6] = (__bf16)av3[2]; afr1[7] = (__bf16)av3[3];
        bf16x8 aE = (bf16x8){0, 0, 0, 0, 0, 0, 0, 0};
        if (quad == 0) {
            aE[0] = (__bf16)pv0; aE[1] = (__bf16)pv1; aE[2] = (__bf16)pv2;
        }

        // ---- issue next tile's prefetch (in flight across ALL compute below) ----
        if (t + 1 < te) {
            int gr = (t + 1) * TR + 16 * w + mr; if (gr > NPTS - 1) gr = NPTS - 1;
            const float* xp = x + (size_t)gr * 64 + quad * 8;
            av0 = *(const f32x4*)(xp);
            av1 = *(const f32x4*)(xp + 4);
            av2 = *(const f32x4*)(xp + 32);
            av3 = *(const f32x4*)(xp + 36);
            pv0 = pos[gr * 3 + 0];
            pv1 = pos[gr * 3 + 1];
            pv2 = pos[gr * 3 + 2];
        }

        // ---- per-tile meta ----
        int rowg[4]; bool rowv[4];
        #pragma unroll
        for (int r = 0; r < 4; ++r) {
            int gr = row0 + quad * 4 + r;
            rowv[r] = (gr < NPTS);
            rowg[r] = batch[gr < NPTS ? gr : NPTS - 1];
        }
        int gf = batch[row0 < NPTS ? row0 : NPTS - 1];
        int rl = row0 + 15; if (rl > NPTS - 1) rl = NPTS - 1;
        int gl = batch[rl];
        float cb0[8];
        #pragma unroll
        for (int t8 = 0; t8 < 8; ++t8) cb0[t8] = cbias[gf * 128 + t8 * 16 + mr];

        // ---- GEMM1 (B from swizzled LDS) + pos.W1p K-extension ----
        f32x4 acc[8];
        #pragma unroll
        for (int t8 = 0; t8 < 8; ++t8) acc[t8] = (f32x4){0.f, 0.f, 0.f, 0.f};
        #pragma unroll
        for (int t8 = 0; t8 < 8; ++t8) {
            int n = t8 * 16 + mr;
            int sw = (n & 7) << 3;
            bf16x8 bv0 = __builtin_bit_cast(bf16x8, *(const u32x4*)(sW1 + ((n * 64 + quad * 8) ^ sw)));
            bf16x8 bv1 = __builtin_bit_cast(bf16x8, *(const u32x4*)(sW1 + ((n * 64 + 32 + quad * 8) ^ sw)));
            acc[t8] = __builtin_amdgcn_mfma_f32_16x16x32_bf16(afr0, bv0, acc[t8], 0, 0, 0);
            acc[t8] = __builtin_amdgcn_mfma_f32_16x16x32_bf16(afr1, bv1, acc[t8], 0, 0, 0);
            acc[t8] = __builtin_amdgcn_mfma_f32_16x16x32_bf16(aE, bfrE[t8], acc[t8], 0, 0, 0);
        }

        // ---- epilogue1: h = relu(acc + cbias[g]) -> wave-private swizzled stripe
        //      (acc fully dies here, BEFORE acc2 exists: proven liveness) ----
        #pragma unroll
        for (int r = 0; r < 4; ++r) {
            int lrow = quad * 4 + r;
            int g = rowg[r];
            bool odd = (g != gf);
            int sw = (lrow & 7) << 3;
            #pragma unroll
            for (int t8 = 0; t8 < 8; ++t8) {
                float cbv = cb0[t8];
                if (odd) cbv = cbias[g * 128 + t8 * 16 + mr];
                float v = fmaxf(acc[t8][r] + cbv, 0.f);
                hsb[lrow * 128 + ((t8 * 16 + mr) ^ sw)] = (__bf16)v;
            }
        }
        // no barrier: GEMM2 reads only this wave's own stripe (same-wave RAW)

        // ---- GEMM2 (A from own h stripe, B from swizzled LDS) ----
        f32x4 acc2[8];
        #pragma unroll
        for (int t8 = 0; t8 < 8; ++t8) acc2[t8] = (f32x4){0.f, 0.f, 0.f, 0.f};
        int swr = (mr & 7) << 3;
        #pragma unroll
        for (int kk = 0; kk < 4; ++kk) {
            bf16x8 a2 = __builtin_bit_cast(bf16x8,
                *(const u32x4*)(hss + mr * 128 + ((kk * 32 + quad * 8) ^ swr)));
            #pragma unroll
            for (int t8 = 0; t8 < 8; ++t8) {
                int n = t8 * 16 + mr;
                bf16x8 bv = __builtin_bit_cast(bf16x8,
                    *(const u32x4*)(sW2 + ((n * 128 + kk * 32 + quad * 8) ^ ((n & 7) << 3))));
                acc2[t8] = __builtin_amdgcn_mfma_f32_16x16x32_bf16(a2, bv, acc2[t8], 0, 0, 0);
            }
        }

        // ---- epilogue2: per-graph column max -> global atomicMax ----
        for (int g = gf; g <= gl; ++g) {
            #pragma unroll
            for (int t8 = 0; t8 < 8; ++t8) {
                float m = -INFINITY;
                #pragma unroll
                for (int r = 0; r < 4; ++r)
                    if (rowv[r] && rowg[r] == g) m = fmaxf(m, acc2[t8][r]);
                m = fmaxf(m, __shfl_xor(m, 16));
                m = fmaxf(m, __shfl_xor(m, 32));
                unsigned mb = __builtin_bit_cast(unsigned, m);
                if (quad == 0 && mb != 0xFF800000u)
                    atomicMax(&outacc[g * 128 + t8 * 16 + mr], mapf(m));
            }
        }
    }
}

__global__ void k_out(const unsigned* __restrict__ outacc,
                      const float* __restrict__ b2v,
                      float* __restrict__ outf) {
    int i = blockIdx.x * 256 + threadIdx.x;   // 8192 threads
    unsigned key = outacc[i];
    float v;
    if (key == 0u) {
        v = -300.f;   // diagnostic: never updated
    } else {
        unsigned bits = (key & 0x80000000u) ? (key & 0x7FFFFFFFu) : ~key;
        union { unsigned u; float f; } c; c.u = bits; v = c.f;
    }
    outf[i] = v + b2v[i & 127];
}

extern "C" void kernel_launch(void* const* d_in, const int* in_sizes, int n_in,
                              void* d_out, int out_size, void* d_ws, size_t ws_size,
                              hipStream_t stream) {
    const float* x   = (const float*)d_in[0];
    const float* pos = (const float*)d_in[1];
    const int*   bat = (const int*)d_in[2];
    const float* lfr = (const float*)d_in[3];
    const float* W1  = (const float*)d_in[4];
    const float* b1  = (const float*)d_in[5];
    const float* W2  = (const float*)d_in[6];
    const float* b2v = (const float*)d_in[7];
    float* outf = (float*)d_out;

    char* ws = (char*)d_ws;
    unsigned*       outacc = (unsigned*)(ws + OFF_OUTACC);
    float*          cbias  = (float*)(ws + OFF_CBIAS);
    float*          W1pT   = (float*)(ws + OFF_W1PT);
    unsigned short* W1aT   = (unsigned short*)(ws + OFF_W1AT);
    unsigned short* W2T    = (unsigned short*)(ws + OFF_W2T);

    k_pre<<<64, 1024, 0, stream>>>(pos, bat, x, W1, b1, W2, lfr,
                                   W1aT, W2T, W1pT, outacc, cbias, outf);
    k_main<<<NBLK, 512, 0, stream>>>(x, pos, bat, W1aT, W2T, W1pT, cbias, outacc);
    k_out<<<32, 256, 0, stream>>>(outacc, b2v, outf);
}

// Round 11
// 256.925 us; speedup vs baseline: 1.8569x; 1.0727x over previous
//
#include <hip/hip_runtime.h>
#include <hip/hip_bf16.h>

#define NPTS 500000
#define NGR  64
#define TR   128
#define NT2  ((NPTS + TR - 1) / TR)   // 3907
#define CHUNK 8
#define NBLK ((NT2 + CHUNK - 1) / CHUNK)   // 489

typedef __bf16 bf16x8 __attribute__((ext_vector_type(8)));
typedef float f32x4 __attribute__((ext_vector_type(4)));
typedef unsigned int u32x4 __attribute__((ext_vector_type(4)));

// ---- workspace layout (bytes), all 16B aligned ----
#define OFF_OUTACC 6144     // u32[8192]: order-preserving max accum
#define OFF_CBIAS  38912    // f32[8192]: per-graph GEMM1 bias row
#define OFF_W1PT   71680    // f32[512] : W1[128:131]^T padded [128][4] (plain)
#define OFF_W1AT   73728    // u16[8192] : bf16 W1[64:128]^T [n=128][k=64], XOR-swizzled
#define OFF_W2T    90112    // u16[16384]: bf16 W2^T [n=128][k=128], XOR-swizzled
// W1AT|W2T contiguous: one 49152-B region staged to LDS in k_main.

// order-preserving float->u32 map (max over u32 == max over float)
__device__ __forceinline__ unsigned mapf(float f) {
    union { float f; unsigned u; } v; v.f = f;
    return ((int)v.u >= 0) ? (v.u | 0x80000000u) : ~v.u;
}

#define GLOAD_LDS16(g, l) __builtin_amdgcn_global_load_lds(                 \
    (__attribute__((address_space(1))) void*)(g),                           \
    (__attribute__((address_space(3))) void*)(l), 16, 0, 0)

// ---- fused pre-pass (one 1024-thread block per graph): proven r7-r10.
//      distributed prep (swizzled W transposes, outacc init) +
//      COM (fp64) + argmin (truncated key) + cbias. No atomics. ----
__global__ __launch_bounds__(1024) void k_pre(
                      const float* __restrict__ pos,
                      const int* __restrict__ batch,
                      const float* __restrict__ x,
                      const float* __restrict__ W1,
                      const float* __restrict__ b1,
                      const float* __restrict__ W2,
                      const float* __restrict__ lfr,
                      unsigned short* __restrict__ W1aT,
                      unsigned short* __restrict__ W2T,
                      float* __restrict__ W1pT,
                      unsigned* __restrict__ outacc,
                      float* __restrict__ cbias,
                      float* __restrict__ outf) {
    __shared__ double sd[16][3];
    __shared__ unsigned long long sk[16];
    __shared__ double scom[3];
    __shared__ int sid;
    __shared__ float sposd[3];
    __shared__ float sp[4][128];
    __shared__ int sse[2];

    int g = blockIdx.x, t = threadIdx.x;
    int lane = t & 63, wv = t >> 6;   // wv 0..15

    // ---- distributed prep: 64*1024 = 65536 threads cover all items ----
    {
        int i = g * 1024 + t;
        if (i < 8192) {
            outacc[i] = 0u;
            int n = i >> 6, k = i & 63;
            unsigned short v = (unsigned short)(__builtin_bit_cast(unsigned, (float)(__bf16)W1[(64 + k) * 128 + n]) >> 16);
            W1aT[i ^ ((n & 7) << 3)] = v;
        } else if (i < 8192 + 16384) {
            int j = i - 8192; int n = j >> 7, k = j & 127;
            unsigned short v = (unsigned short)(__builtin_bit_cast(unsigned, (float)(__bf16)W2[k * 128 + n]) >> 16);
            W2T[j ^ ((n & 7) << 3)] = v;
        } else if (i < 8192 + 16384 + 512) {
            int j = i - 24576; int n = j >> 2, q = j & 3;
            W1pT[j] = (q < 3) ? W1[(128 + q) * 128 + n] : 0.f;
        }
    }

    // ---- own-range binary search (batch is sorted) ----
    if (t < 2) {
        int target = g + t;
        int lo = 0, hi = NPTS;
        while (lo < hi) {
            int mid = (lo + hi) >> 1;
            if (batch[mid] < target) lo = mid + 1; else hi = mid;
        }
        sse[t] = lo;
    }
    __syncthreads();
    int s = sse[0], e = sse[1];

    // pass 1: fp64 position sums
    double sx = 0.0, sy = 0.0, sz = 0.0;
    for (int i = s + t; i < e; i += 1024) {
        sx += (double)pos[i * 3 + 0];
        sy += (double)pos[i * 3 + 1];
        sz += (double)pos[i * 3 + 2];
    }
    #pragma unroll
    for (int m = 1; m < 64; m <<= 1) {
        sx += __shfl_xor(sx, m);
        sy += __shfl_xor(sy, m);
        sz += __shfl_xor(sz, m);
    }
    if (lane == 0) { sd[wv][0] = sx; sd[wv][1] = sy; sd[wv][2] = sz; }
    __syncthreads();
    if (t == 0) {
        double ax = 0.0, ay = 0.0, az = 0.0;
        for (int q = 0; q < 16; ++q) { ax += sd[q][0]; ay += sd[q][1]; az += sd[q][2]; }
        double cnt = (double)(e - s);
        double rc = 1.0 / (cnt > 1.0 ? cnt : 1.0);
        scom[0] = ax * rc; scom[1] = ay * rc; scom[2] = az * rc;
    }
    __syncthreads();
    double cx = scom[0], cy = scom[1], cz = scom[2];

    // pass 2: argmin of fp64 d2, key = (trunc d2-bits) | id
    unsigned long long key = ~0ULL;
    for (int i = s + t; i < e; i += 1024) {
        double dx = (double)pos[i * 3 + 0] - cx;
        double dy = (double)pos[i * 3 + 1] - cy;
        double dz = (double)pos[i * 3 + 2] - cz;
        double d2 = __builtin_fma(dx, dx, __builtin_fma(dy, dy, dz * dz));
        unsigned long long b = __builtin_bit_cast(unsigned long long, d2);
        unsigned long long k2 = (b & ~0xFFFFFULL) | (unsigned long long)i;
        key = k2 < key ? k2 : key;
    }
    #pragma unroll
    for (int m = 1; m < 64; m <<= 1) {
        unsigned long long o = __shfl_xor(key, m);
        key = o < key ? o : key;
    }
    if (lane == 0) sk[wv] = key;
    __syncthreads();
    if (t == 0) {
        unsigned long long k = sk[0];
        for (int q = 1; q < 16; ++q) if (sk[q] < k) k = sk[q];
        int id = (int)(k & 0xFFFFFULL);
        if (id > NPTS - 1) id = NPTS - 1;
        sid = id;
    }
    __syncthreads();
    int id = sid;

    if (t < 3) {
        float p = pos[id * 3 + t];
        sposd[t] = p;
        outf[8192 + g * 3 + t] = p;
    }
    if (t == 4) outf[8192 + 192 + g] = (float)batch[id];
    if (t < 9) outf[8192 + 256 + g * 9 + t] = lfr[id * 9 + t];

    // cbias: 4-way split over k, then ordered combine
    if (t < 512) {
        int c = t & 127, p = t >> 7;
        float part = 0.f;
        #pragma unroll
        for (int kq = 0; kq < 16; ++kq) {
            int k = p * 16 + kq;
            float xd = x[id * 64 + k];
            part += xd * (W1[k * 128 + c] - W1[(64 + k) * 128 + c]);
        }
        sp[p][c] = part;
    }
    __syncthreads();
    if (t < 128) {
        int c = t;
        float sv = b1[c] + sp[0][c] + sp[1][c] + sp[2][c] + sp[3][c];
        sv -= sposd[0] * W1[128 * 128 + c] + sposd[1] * W1[129 * 128 + c] + sposd[2] * W1[130 * 128 + c];
        cbias[g * 128 + c] = sv;
    }
}

// ---- main: r10 structure (M=16, (512,2), LDS 81920 -> 2 blocks/CU, prefetch)
//      + (1) batch-meta prefetched for t+1, (2) cb0 persistent across tiles
//      (reload only on graph change, at body bottom), (3) wave-uniform
//      fast/slow epilogue split (interior single-graph tiles skip rowg loads,
//      cbias selects, and the multi-g epi2 loop), (4) CHUNK=8 (one resident
//      round of 489 blocks). Register budget ~112 < 128 cap. ----
__global__ __launch_bounds__(512, 2) void k_main(
    const float* __restrict__ x,
    const float* __restrict__ pos,
    const int* __restrict__ batch,
    const unsigned short* __restrict__ W1aT,
    const unsigned short* __restrict__ W2T,
    const float* __restrict__ W1pT,
    const float* __restrict__ cbias,
    unsigned* __restrict__ outacc)
{
    // [0,16384): W1aT swizzled bf16 [128][64]
    // [16384,49152): W2T swizzled bf16 [128][128]
    // [49152,81920): h stripes: 8 waves x [16][128] bf16 XOR-swizzled (4096 B)
    __shared__ alignas(16) unsigned char smem[81920];

    const int tid  = threadIdx.x;        // 0..511
    const int w    = tid >> 6;           // 0..7
    const int lane = tid & 63;
    const int quad = lane >> 4;
    const int mr   = lane & 15;

    // stage W once (linear copy; global layout is pre-swizzled; 3072 x 16B)
    #pragma unroll
    for (int i = 0; i < 6; ++i)
        GLOAD_LDS16((const char*)W1aT + (i * 512 + tid) * 16,
                    (char*)smem + (i * 512 + tid) * 16);

    // tile-invariant: B-ext fragments for pos.W1p K-extension
    bf16x8 bfrE[8];
    #pragma unroll
    for (int t8 = 0; t8 < 8; ++t8) {
        f32x4 wp = *(const f32x4*)(W1pT + (t8 * 16 + mr) * 4);
        bf16x8 e = (bf16x8){0, 0, 0, 0, 0, 0, 0, 0};
        if (quad == 0) { e[0] = (__bf16)wp[0]; e[1] = (__bf16)wp[1]; e[2] = (__bf16)wp[2]; }
        bfrE[t8] = e;
    }

    __syncthreads();   // W staged; the only block-wide barrier in this kernel

    const unsigned short* sW1 = (const unsigned short*)smem;
    const unsigned short* sW2 = (const unsigned short*)(smem + 16384);
    __bf16* hsb = (__bf16*)(smem + 49152) + w * 2048;   // [16][128] swizzled
    const unsigned short* hss = (const unsigned short*)hsb;

    const int tb = blockIdx.x * CHUNK;
    int te = tb + CHUNK; if (te > NT2) te = NT2;

    // ---- prefetch first tile: x (4x dwordx4), pos (3 scalars), batch meta ----
    f32x4 av0, av1, av2, av3;
    float pv0, pv1, pv2;
    int gf, gl;
    {
        int gr = tb * TR + 16 * w + mr; if (gr > NPTS - 1) gr = NPTS - 1;
        const float* xp = x + (size_t)gr * 64 + quad * 8;
        av0 = *(const f32x4*)(xp);
        av1 = *(const f32x4*)(xp + 4);
        av2 = *(const f32x4*)(xp + 32);
        av3 = *(const f32x4*)(xp + 36);
        pv0 = pos[gr * 3 + 0];
        pv1 = pos[gr * 3 + 1];
        pv2 = pos[gr * 3 + 2];
        int r0 = tb * TR + 16 * w;
        gf = batch[r0 < NPTS ? r0 : NPTS - 1];
        int rl = r0 + 15; if (rl > NPTS - 1) rl = NPTS - 1;
        gl = batch[rl];
    }
    // persistent cbias row for current gf
    float cb0[8];
    #pragma unroll
    for (int t8 = 0; t8 < 8; ++t8) cb0[t8] = cbias[gf * 128 + t8 * 16 + mr];

    for (int t = tb; t < te; ++t) {
        const int row0 = t * TR + 16 * w;   // this wave's 16 global rows

        // ---- extract fragments from prefetched registers ----
        bf16x8 afr0, afr1;
        afr0[0] = (__bf16)av0[0]; afr0[1] = (__bf16)av0[1]; afr0[2] = (__bf16)av0[2]; afr0[3] = (__bf16)av0[3];
        afr0[4] = (__bf16)av1[0]; afr0[5] = (__bf16)av1[1]; afr0[6] = (__bf16)av1[2]; afr0[7] = (__bf16)av1[3];
        afr1[0] = (__bf16)av2[0]; afr1[1] = (__bf16)av2[1]; afr1[2] = (__bf16)av2[2]; afr1[3] = (__bf16)av2[3];
        afr1[4] = (__bf16)av3[0]; afr1[5] = (__bf16)av3[1]; afr1[6] = (__bf16)av3[2]; afr1[7] = (__bf16)av3[3];
        bf16x8 aE = (bf16x8){0, 0, 0, 0, 0, 0, 0, 0};
        if (quad == 0) {
            aE[0] = (__bf16)pv0; aE[1] = (__bf16)pv1; aE[2] = (__bf16)pv2;
        }

        // ---- issue next tile's prefetch (x, pos, batch meta; in flight
        //      across ALL compute below) ----
        int gfn = gf, gln = gl;
        if (t + 1 < te) {
            int gr = (t + 1) * TR + 16 * w + mr; if (gr > NPTS - 1) gr = NPTS - 1;
            const float* xp = x + (size_t)gr * 64 + quad * 8;
            av0 = *(const f32x4*)(xp);
            av1 = *(const f32x4*)(xp + 4);
            av2 = *(const f32x4*)(xp + 32);
            av3 = *(const f32x4*)(xp + 36);
            pv0 = pos[gr * 3 + 0];
            pv1 = pos[gr * 3 + 1];
            pv2 = pos[gr * 3 + 2];
            int r0n = (t + 1) * TR + 16 * w;
            gfn = batch[r0n < NPTS ? r0n : NPTS - 1];
            int rln = r0n + 15; if (rln > NPTS - 1) rln = NPTS - 1;
            gln = batch[rln];
        }

        // ---- GEMM1 (B from swizzled LDS) + pos.W1p K-extension ----
        f32x4 acc[8];
        #pragma unroll
        for (int t8 = 0; t8 < 8; ++t8) acc[t8] = (f32x4){0.f, 0.f, 0.f, 0.f};
        #pragma unroll
        for (int t8 = 0; t8 < 8; ++t8) {
            int n = t8 * 16 + mr;
            int sw = (n & 7) << 3;
            bf16x8 bv0 = __builtin_bit_cast(bf16x8, *(const u32x4*)(sW1 + ((n * 64 + quad * 8) ^ sw)));
            bf16x8 bv1 = __builtin_bit_cast(bf16x8, *(const u32x4*)(sW1 + ((n * 64 + 32 + quad * 8) ^ sw)));
            acc[t8] = __builtin_amdgcn_mfma_f32_16x16x32_bf16(afr0, bv0, acc[t8], 0, 0, 0);
            acc[t8] = __builtin_amdgcn_mfma_f32_16x16x32_bf16(afr1, bv1, acc[t8], 0, 0, 0);
            acc[t8] = __builtin_amdgcn_mfma_f32_16x16x32_bf16(aE, bfrE[t8], acc[t8], 0, 0, 0);
        }

        // ---- epilogue1: h = relu(acc + cbias) -> wave-private swizzled stripe.
        //      Wave-uniform fast path: single-graph, fully in-bounds tile. ----
        const bool fast = (gf == gl) && (row0 + 15 < NPTS);
        int rowg[4]; bool rowv[4];
        if (fast) {
            #pragma unroll
            for (int r = 0; r < 4; ++r) {
                int lrow = quad * 4 + r;
                int sw = (lrow & 7) << 3;
                #pragma unroll
                for (int t8 = 0; t8 < 8; ++t8) {
                    float v = fmaxf(acc[t8][r] + cb0[t8], 0.f);
                    hsb[lrow * 128 + ((t8 * 16 + mr) ^ sw)] = (__bf16)v;
                }
            }
        } else {
            #pragma unroll
            for (int r = 0; r < 4; ++r) {
                int gr = row0 + quad * 4 + r;
                rowv[r] = (gr < NPTS);
                rowg[r] = batch[gr < NPTS ? gr : NPTS - 1];
            }
            #pragma unroll
            for (int r = 0; r < 4; ++r) {
                int lrow = quad * 4 + r;
                int g = rowg[r];
                bool odd = (g != gf);
                int sw = (lrow & 7) << 3;
                #pragma unroll
                for (int t8 = 0; t8 < 8; ++t8) {
                    float cbv = cb0[t8];
                    if (odd) cbv = cbias[g * 128 + t8 * 16 + mr];
                    float v = fmaxf(acc[t8][r] + cbv, 0.f);
                    hsb[lrow * 128 + ((t8 * 16 + mr) ^ sw)] = (__bf16)v;
                }
            }
        }
        // no barrier: GEMM2 reads only this wave's own stripe (same-wave RAW)

        // ---- GEMM2 (A from own h stripe, B from swizzled LDS) ----
        f32x4 acc2[8];
        #pragma unroll
        for (int t8 = 0; t8 < 8; ++t8) acc2[t8] = (f32x4){0.f, 0.f, 0.f, 0.f};
        int swr = (mr & 7) << 3;
        #pragma unroll
        for (int kk = 0; kk < 4; ++kk) {
            bf16x8 a2 = __builtin_bit_cast(bf16x8,
                *(const u32x4*)(hss + mr * 128 + ((kk * 32 + quad * 8) ^ swr)));
            #pragma unroll
            for (int t8 = 0; t8 < 8; ++t8) {
                int n = t8 * 16 + mr;
                bf16x8 bv = __builtin_bit_cast(bf16x8,
                    *(const u32x4*)(sW2 + ((n * 128 + kk * 32 + quad * 8) ^ ((n & 7) << 3))));
                acc2[t8] = __builtin_amdgcn_mfma_f32_16x16x32_bf16(a2, bv, acc2[t8], 0, 0, 0);
            }
        }

        // ---- epilogue2: per-graph column max -> global atomicMax ----
        if (fast) {
            #pragma unroll
            for (int t8 = 0; t8 < 8; ++t8) {
                float m = fmaxf(fmaxf(acc2[t8][0], acc2[t8][1]),
                                fmaxf(acc2[t8][2], acc2[t8][3]));
                m = fmaxf(m, __shfl_xor(m, 16));
                m = fmaxf(m, __shfl_xor(m, 32));
                if (quad == 0)
                    atomicMax(&outacc[gf * 128 + t8 * 16 + mr], mapf(m));
            }
        } else {
            for (int g = gf; g <= gl; ++g) {
                #pragma unroll
                for (int t8 = 0; t8 < 8; ++t8) {
                    float m = -INFINITY;
                    #pragma unroll
                    for (int r = 0; r < 4; ++r)
                        if (rowv[r] && rowg[r] == g) m = fmaxf(m, acc2[t8][r]);
                    m = fmaxf(m, __shfl_xor(m, 16));
                    m = fmaxf(m, __shfl_xor(m, 32));
                    unsigned mb = __builtin_bit_cast(unsigned, m);
                    if (quad == 0 && mb != 0xFF800000u)
                        atomicMax(&outacc[g * 128 + t8 * 16 + mr], mapf(m));
                }
            }
        }

        // ---- rotate meta; reload cb0 only on graph change (covered by
        //      next tile's GEMM1) ----
        if (t + 1 < te) {
            if (gfn != gf) {
                #pragma unroll
                for (int t8 = 0; t8 < 8; ++t8) cb0[t8] = cbias[gfn * 128 + t8 * 16 + mr];
            }
            gf = gfn; gl = gln;
        }
    }
}

__global__ void k_out(const unsigned* __restrict__ outacc,
                      const float* __restrict__ b2v,
                      float* __restrict__ outf) {
    int i = blockIdx.x * 256 + threadIdx.x;   // 8192 threads
    unsigned key = outacc[i];
    float v;
    if (key == 0u) {
        v = -300.f;   // diagnostic: never updated
    } else {
        unsigned bits = (key & 0x80000000u) ? (key & 0x7FFFFFFFu) : ~key;
        union { unsigned u; float f; } c; c.u = bits; v = c.f;
    }
    outf[i] = v + b2v[i & 127];
}

extern "C" void kernel_launch(void* const* d_in, const int* in_sizes, int n_in,
                              void* d_out, int out_size, void* d_ws, size_t ws_size,
                              hipStream_t stream) {
    const float* x   = (const float*)d_in[0];
    const float* pos = (const float*)d_in[1];
    const int*   bat = (const int*)d_in[2];
    const float* lfr = (const float*)d_in[3];
    const float* W1  = (const float*)d_in[4];
    const float* b1  = (const float*)d_in[5];
    const float* W2  = (const float*)d_in[6];
    const float* b2v = (const float*)d_in[7];
    float* outf = (float*)d_out;

    char* ws = (char*)d_ws;
    unsigned*       outacc = (unsigned*)(ws + OFF_OUTACC);
    float*          cbias  = (float*)(ws + OFF_CBIAS);
    float*          W1pT   = (float*)(ws + OFF_W1PT);
    unsigned short* W1aT   = (unsigned short*)(ws + OFF_W1AT);
    unsigned short* W2T    = (unsigned short*)(ws + OFF_W2T);

    k_pre<<<64, 1024, 0, stream>>>(pos, bat, x, W1, b1, W2, lfr,
                                   W1aT, W2T, W1pT, outacc, cbias, outf);
    k_main<<<NBLK, 512, 0, stream>>>(x, pos, bat, W1aT, W2T, W1pT, cbias, outacc);
    k_out<<<32, 256, 0, stream>>>(outacc, b2v, outf);
}